// Round 2
// baseline (2567.740 us; speedup 1.0000x reference)
//
#include <hip/hip_runtime.h>
#include <math.h>

#define BB 256
#define LL 20
#define HH 128
#define NH 8
#define D2C 64
#define NTY 4
#define NRL 4
#define CHILDN 30001
#define PARENTN 500
#define N1SN 50000
#define N1DN 20000
#define E1N 300000
#define N2N 20000
#define E2N 200000
#define TT (BB*LL)
#define N4DN 5000
#define E4N 150000
#define EC2PN 8000

__device__ __forceinline__ unsigned fenc(float f){ unsigned u=__float_as_uint(f); return (u&0x80000000u)? ~u : (u|0x80000000u); }
__device__ __forceinline__ float fdec(unsigned u){ return (u&0x80000000u)? __uint_as_float(u^0x80000000u) : __uint_as_float(~u); }
__device__ __forceinline__ float sigf(float x){ return 1.f/(1.f+expf(-x)); }

// ---------------- Stage A: feature expansion ----------------
// grid = B*L blocks (bl = b*LL+l), 128 threads
__global__ void k_featx(const int* seq, const int* dur, const int* stime, const int* etime,
                        const float* emb, const float* dia_w, const float* dia_b,
                        const float* t2v_w, const float* t2v_b,
                        const float* exp_W, const float* exp_b, float* xout){
  int bl = blockIdx.x; int o = threadIdx.x;
  __shared__ float feat[272];
  int node = seq[bl];
  float ts = (float)stime[bl], te = (float)etime[bl], td = (float)dur[bl];
  float e0 = emb[node*HH+o];
  float st, et;
  if(o < D2C){ st = e0; et = e0; }
  else {
    float w = dia_w[node*HH+o], b = dia_b[node*HH+o];
    st = e0 * sinf(w*ts + b);
    et = e0 * sinf(w*te + b);
  }
  feat[o] = st; feat[HH+o] = et;
  if(o < 16){
    float w = t2v_w[o], b = t2v_b[o];
    feat[256+o] = (o==0) ? (w*td + b) : sinf(w*td + b);
  }
  __syncthreads();
  float acc = exp_b[o];
  for(int j=0;j<272;j++) acc += feat[j]*exp_W[j*HH+o];
  xout[bl*HH+o] = fmaxf(acc, 0.f);
}

// x (rows of H) @ Wi (H,512) + b -> gpre ; grid = rows, 512 threads
__global__ void k_xwi(const float* x, const float* Wi, const float* bias, float* gpre){
  int row = blockIdx.x; int o = threadIdx.x;
  __shared__ float xs[HH];
  if(o < HH) xs[o] = x[row*HH+o];
  __syncthreads();
  float acc = bias[o];
  for(int h=0;h<HH;h++) acc += xs[h]*Wi[h*512+o];
  gpre[row*512+o] = acc;
}

// grid = BB blocks, 512 threads; writes hout (B,L,H) and optional second copy
__global__ void k_lstm(const float* gpre, const float* Wh, float* hout, float* hout2){
  int b = blockIdx.x; int o = threadIdx.x;
  __shared__ float hs[HH];
  __shared__ float gs[512];
  float c = 0.f;
  if(o < HH) hs[o] = 0.f;
  __syncthreads();
  for(int l=0;l<LL;l++){
    float acc = gpre[(b*LL+l)*512+o];
    for(int h=0;h<HH;h++) acc += hs[h]*Wh[h*512+o];
    gs[o] = acc;
    __syncthreads();
    if(o < HH){
      float ig = sigf(gs[o]);
      float fg = sigf(gs[HH+o]);
      float gg = tanhf(gs[2*HH+o]);
      float og = sigf(gs[3*HH+o]);
      c = fg*c + ig*gg;
      float h = og*tanhf(c);
      hs[o] = h;
      hout[(b*LL+l)*HH+o] = h;
      if(hout2) hout2[(b*LL+l)*HH+o] = h;
    }
    __syncthreads();
  }
}

__global__ void k_tok(const int* seq, const int* seq_nt, int* tokid, int* toknt){
  int t = blockIdx.x*blockDim.x + threadIdx.x;
  if(t >= TT) return;
  int b = t % BB, l = t / BB;
  tokid[t] = seq[b*LL+l];
  toknt[t] = seq_nt[b*LL+l];
}

// ---------------- generic HTGT conv pieces ----------------
__global__ void k_gather_emb(const int* nid, const float* emb, float* dst){
  int i = blockIdx.x; int o = threadIdx.x;
  dst[i*HH+o] = emb[nid[i]*HH+o];
}

__global__ void k_prep2(const int* sel, const float* xg, const int* g1_nid, const int* g1_nt,
                        float* srcbuf, int* gnid2, int* tsrc2){
  int i = blockIdx.x; int o = threadIdx.x;
  int s = sel[i];
  srcbuf[i*HH+o] = xg[s*HH+o];
  if(o==0){ gnid2[i] = g1_nid[s]; tsrc2[i] = g1_nt[s]; }
}

__global__ void k_dst2(const int* tok_sel, const float* xg, const float* h1, float* dst2){
  int t = blockIdx.x; int o = threadIdx.x;
  int b = t % BB, l = t / BB;
  dst2[t*HH+o] = xg[tok_sel[t]*HH+o] + h1[(b*LL+l)*HH+o];
}

__global__ void k_x0(const int* nid, const int* ntype, const float* emb, const float* hist2,
                     const float* skip, float* srcbuf){
  int i = blockIdx.x; int o = threadIdx.x;
  float a = sigf(skip[ntype[i]]);
  int nd = nid[i];
  srcbuf[i*HH+o] = emb[nd*HH+o]*a + hist2[nd*HH+o]*(1.f-a);
}

// LN + time-mod + K,V projections; grid = nsrc, 128 threads
__global__ void k_conv_kv(const float* src_h, const int* src_nid, const int* src_t,
                          const float* dia_w, const float* dia_b,
                          const float* KW, const float* VW, float* Kbuf, float* Vbuf){
  int i = blockIdx.x; int o = threadIdx.x;
  __shared__ float hs[HH];
  __shared__ float red[HH];
  float v = src_h[i*HH+o];
  red[o] = v; __syncthreads();
  for(int s=64;s>0;s>>=1){ if(o<s) red[o]+=red[o+s]; __syncthreads(); }
  float mean = red[0]/(float)HH;
  __syncthreads();
  red[o] = v*v; __syncthreads();
  for(int s=64;s>0;s>>=1){ if(o<s) red[o]+=red[o+s]; __syncthreads(); }
  float var = red[0]/(float)HH - mean*mean;
  float h = (v-mean)*(1.f/sqrtf(fmaxf(var,0.f)+1e-5f));
  if(o >= D2C){
    int nd = src_nid[i];
    h *= sinf(dia_w[nd*HH+o] + dia_b[nd*HH+o]);
  }
  __syncthreads();
  hs[o] = h; __syncthreads();
  int t = src_t[i];
  const float* kw = KW + (size_t)t*HH*HH;
  const float* vw = VW + (size_t)t*HH*HH;
  float ka = 0.f, va = 0.f;
  for(int j=0;j<HH;j++){ float x = hs[j]; ka += x*kw[j*HH+o]; va += x*vw[j*HH+o]; }
  Kbuf[i*HH+o] = ka; Vbuf[i*HH+o] = va;
}

// LN + Q projection; grid = ndst, 128 threads
__global__ void k_conv_q(const float* dst_h, const int* dst_t, const float* QW, float* Qbuf){
  int i = blockIdx.x; int o = threadIdx.x;
  __shared__ float hs[HH];
  __shared__ float red[HH];
  float v = dst_h[i*HH+o];
  red[o] = v; __syncthreads();
  for(int s=64;s>0;s>>=1){ if(o<s) red[o]+=red[o+s]; __syncthreads(); }
  float mean = red[0]/(float)HH;
  __syncthreads();
  red[o] = v*v; __syncthreads();
  for(int s=64;s>0;s>>=1){ if(o<s) red[o]+=red[o+s]; __syncthreads(); }
  float var = red[0]/(float)HH - mean*mean;
  float h = (v-mean)*(1.f/sqrtf(fmaxf(var,0.f)+1e-5f));
  __syncthreads();
  hs[o] = h; __syncthreads();
  const float* qw = QW + (size_t)dst_t[i]*HH*HH;
  float qa = 0.f;
  for(int j=0;j<HH;j++) qa += hs[j]*qw[j*HH+o];
  Qbuf[i*HH+o] = qa;
}

__global__ void k_conv_init(float* Abuf, float* Dbuf, unsigned* Mbuf, int nd){
  int i = blockIdx.x*blockDim.x + threadIdx.x;
  if(i < nd*HH) Abuf[i] = 0.f;
  if(i < nd*NH){ Dbuf[i] = 0.f; Mbuf[i] = 0x007FFFFFu; }
}

// one wave per edge (4 edges / 256-thread block)
__global__ void k_conv_score(const int* esrc, const int* edst, const int* etype, const int* ew,
                             const float* edge_emb, const float* EWp, const float* mu,
                             const float* Kbuf, const float* Qbuf,
                             float* Sbuf, unsigned* Mbuf, int E){
  int e = blockIdx.x*4 + (threadIdx.x>>6);
  if(e >= E) return;
  int lane = threadIdx.x & 63;
  int src = esrc[e], dst = edst[e];
  const float* ee = edge_emb + (size_t)ew[e]*32;
  int d1 = lane, d2 = lane + 64;
  float em1 = 0.f, em2 = 0.f;
  for(int j=0;j<32;j++){
    float x = ee[j];
    em1 += x*EWp[j*HH+d1];
    em2 += x*EWp[j*HH+d2];
  }
  float p1 = Qbuf[dst*HH+d1]*(Kbuf[src*HH+d1]+em1);
  float p2 = Qbuf[dst*HH+d2]*(Kbuf[src*HH+d2]+em2);
  for(int off=8;off>0;off>>=1){
    p1 += __shfl_xor(p1, off, 64);
    p2 += __shfl_xor(p2, off, 64);
  }
  if((lane & 15) == 0){
    int h1 = lane>>4, h2 = 4 + (lane>>4);
    int ty = etype[e];
    float s1 = p1 * mu[ty*NH+h1] * 0.25f;
    float s2 = p2 * mu[ty*NH+h2] * 0.25f;
    Sbuf[e*8+h1] = s1; Sbuf[e*8+h2] = s2;
    atomicMax(&Mbuf[dst*8+h1], fenc(s1));
    atomicMax(&Mbuf[dst*8+h2], fenc(s2));
  }
}

__global__ void k_conv_expsum(const int* edst, float* Sbuf, const unsigned* Mbuf, float* Dbuf, int E){
  int i = blockIdx.x*blockDim.x + threadIdx.x;
  if(i >= E*8) return;
  int e = i>>3, h = i&7;
  int dst = edst[e];
  float m = fdec(Mbuf[dst*8+h]);
  float ex = expf(Sbuf[i]-m);
  Sbuf[i] = ex;
  atomicAdd(&Dbuf[dst*8+h], ex);
}

__global__ void k_conv_agg(const int* esrc, const int* edst, const float* Sbuf, const float* Dbuf,
                           const float* Vbuf, float* Abuf, int E){
  int e = blockIdx.x*4 + (threadIdx.x>>6);
  if(e >= E) return;
  int lane = threadIdx.x & 63;
  int src = esrc[e], dst = edst[e];
  int h1 = lane>>4, h2 = 4 + (lane>>4);
  float a1 = Sbuf[e*8+h1]/fmaxf(Dbuf[dst*8+h1],1e-9f);
  float a2 = Sbuf[e*8+h2]/fmaxf(Dbuf[dst*8+h2],1e-9f);
  atomicAdd(&Abuf[dst*HH+lane],    a1*Vbuf[src*HH+lane]);
  atomicAdd(&Abuf[dst*HH+lane+64], a2*Vbuf[src*HH+lane+64]);
}

__global__ void k_conv_out(const float* Abuf, const int* dst_t, const float* OW,
                           const float* dst_h, float* out, float* out2, int relu){
  int i = blockIdx.x; int o = threadIdx.x;
  __shared__ float as[HH];
  as[o] = Abuf[i*HH+o]; __syncthreads();
  const float* w = OW + (size_t)dst_t[i]*HH*HH;
  float acc = dst_h[i*HH+o];
  for(int j=0;j<HH;j++) acc += as[j]*w[j*HH+o];
  if(relu) acc = fmaxf(acc, 0.f);
  out[i*HH+o] = acc;
  if(out2) out2[i*HH+o] = acc;
}

// ---------------- stage D: token pooling ----------------
__global__ void k_seq2(const float* x2, float* xout){
  int bl = blockIdx.x; int o = threadIdx.x;
  int b = bl / LL, l = bl % LL;
  xout[bl*HH+o] = x2[(l*BB+b)*HH+o];
}

__global__ void k_zero_hist(float* hist2, float* cnt, unsigned* amax, float* aden){
  int i = blockIdx.x*blockDim.x + threadIdx.x;
  if(i < CHILDN*HH) hist2[i] = 0.f;
  if(i < CHILDN){ cnt[i] = 0.f; aden[i] = 0.f; amax[i] = 0x007FFFFFu; }
}

__global__ void k_tokatt(const float* h2f, const int* toknt, const float* ipW, const float* iaW,
                         float* abuf, unsigned* amax, const int* tokid){
  int t = blockIdx.x; int o = threadIdx.x;
  __shared__ float es[HH];
  __shared__ float red[HH];
  int b = t % BB, l = t / BB;
  es[o] = h2f[(b*LL+l)*HH+o];
  __syncthreads();
  int nt = toknt[t];
  const float* w = ipW + (size_t)nt*HH*HH;
  float acc = 0.f;
  for(int j=0;j<HH;j++) acc += es[j]*w[j*HH+o];
  float u = tanhf(acc);
  red[o] = u * iaW[nt*HH+o];
  __syncthreads();
  for(int s=64;s>0;s>>=1){ if(o<s) red[o]+=red[o+s]; __syncthreads(); }
  if(o==0){
    float a = red[0];
    abuf[t] = a;
    atomicMax(&amax[tokid[t]], fenc(a));
  }
}

__global__ void k_tokexp(const int* tokid, float* abuf, const unsigned* amax, float* aden, float* cnt){
  int t = blockIdx.x*blockDim.x + threadIdx.x;
  if(t >= TT) return;
  int c = tokid[t];
  float ex = expf(abuf[t]-fdec(amax[c]));
  abuf[t] = ex;
  atomicAdd(&aden[c], ex);
  atomicAdd(&cnt[c], 1.f);
}

__global__ void k_tokagg(const int* tokid, const float* abuf, const float* aden,
                         const float* h2f, float* hist2){
  int t = blockIdx.x; int o = threadIdx.x;
  int c = tokid[t];
  float w = abuf[t]/fmaxf(aden[c],1e-9f);
  int b = t % BB, l = t / BB;
  atomicAdd(&hist2[c*HH+o], w*h2f[(b*LL+l)*HH+o]);
}

__global__ void k_histfix(const float* cnt, const float* hist_emb, float* hist2){
  int c = blockIdx.x; int o = threadIdx.x;
  if(cnt[c] == 0.f) hist2[c*HH+o] = hist_emb[c*HH+o];
}

// ---------------- parent pooling ----------------
__global__ void k_zero_parent(float* psum, float* pcnt){
  int i = blockIdx.x*blockDim.x + threadIdx.x;
  if(i < PARENTN*HH) psum[i] = 0.f;
  if(i < PARENTN) pcnt[i] = 0.f;
}

__global__ void k_peagg(const int* pe_p, const int* pe_c, const float* cef, float* psum, float* pcnt){
  int i = blockIdx.x; int o = threadIdx.x;
  int p = pe_p[i], c = pe_c[i];
  atomicAdd(&psum[p*HH+o], cef[c*HH+o]);
  if(o==0) atomicAdd(&pcnt[p], 1.f);
}

__global__ void k_parent(const float* psum, const float* pcnt, float* out){
  int i = blockIdx.x; int o = threadIdx.x;
  out[i*HH+o] = psum[i*HH+o]/fmaxf(pcnt[i],1.f);
}

extern "C" void kernel_launch(void* const* d_in, const int* in_sizes, int n_in,
                              void* d_out, int out_size, void* d_ws, size_t ws_size,
                              hipStream_t stream){
  const int* seq     = (const int*)d_in[0];
  const int* seq_nt  = (const int*)d_in[1];
  const int* dur     = (const int*)d_in[2];
  const int* stime   = (const int*)d_in[3];
  const int* etime   = (const int*)d_in[4];
  const int* g1_nid  = (const int*)d_in[5];
  const int* g1_nt   = (const int*)d_in[6];
  const int* g1_esrc = (const int*)d_in[7];
  const int* g1_edst = (const int*)d_in[8];
  const int* g1_ety  = (const int*)d_in[9];
  const int* g1_ew   = (const int*)d_in[10];
  const int* g2_sel  = (const int*)d_in[11];
  const int* g2_esrc = (const int*)d_in[12];
  const int* g2_edst = (const int*)d_in[13];
  const int* g2_ety  = (const int*)d_in[14];
  const int* g2_ew   = (const int*)d_in[15];
  const int* tok_sel = (const int*)d_in[16];
  const int* g4_esrc = (const int*)d_in[17];
  const int* g4_edst = (const int*)d_in[18];
  const int* g4_ety  = (const int*)d_in[19];
  const int* g4_ew   = (const int*)d_in[20];
  const int* pe_p    = (const int*)d_in[21];
  const int* pe_c    = (const int*)d_in[22];
  const float* emb     = (const float*)d_in[23];
  const float* hist_emb= (const float*)d_in[24];
  const float* edge_emb= (const float*)d_in[25];
  const float* dia_w   = (const float*)d_in[26];
  const float* dia_b   = (const float*)d_in[27];
  const float* t2v_w   = (const float*)d_in[28];
  const float* t2v_b   = (const float*)d_in[29];
  const float* exp_W   = (const float*)d_in[30];
  const float* exp_b   = (const float*)d_in[31];
  const float* l1Wi    = (const float*)d_in[32];
  const float* l1Wh    = (const float*)d_in[33];
  const float* l1b     = (const float*)d_in[34];
  const float* l2Wi    = (const float*)d_in[35];
  const float* l2Wh    = (const float*)d_in[36];
  const float* l2b     = (const float*)d_in[37];
  const float* convK   = (const float*)d_in[38];
  const float* convQ   = (const float*)d_in[39];
  const float* convV   = (const float*)d_in[40];
  const float* convO   = (const float*)d_in[41];
  const float* convE   = (const float*)d_in[42];
  const float* convMu  = (const float*)d_in[43];
  const float* ipW     = (const float*)d_in[44];
  const float* iaW     = (const float*)d_in[45];
  const float* skip    = (const float*)d_in[46];
  float* outp = (float*)d_out;

  // workspace arena
  char* wsp = (char*)d_ws;
  size_t off = 0;
  auto A = [&](size_t nbytes)->char*{ char* p = wsp+off; off += (nbytes+255)&~(size_t)255; return p; };
  float*    srcbuf = (float*)   A((size_t)N1SN*HH*4);
  float*    Kbuf   = (float*)   A((size_t)N1SN*HH*4);
  float*    Vbuf   = (float*)   A((size_t)N1SN*HH*4);
  float*    Qbuf   = (float*)   A((size_t)N1DN*HH*4);
  float*    Sbuf   = (float*)   A((size_t)E1N*8*4);
  unsigned* Mbuf   = (unsigned*)A((size_t)N1DN*8*4);
  float*    Dbuf   = (float*)   A((size_t)N1DN*8*4);
  float*    Abuf   = (float*)   A((size_t)N1DN*HH*4);
  float*    xbuf   = (float*)   A((size_t)TT*HH*4);
  float*    gpre   = (float*)   A((size_t)TT*512*4);
  float*    h1     = (float*)   A((size_t)TT*HH*4);
  float*    dst2   = (float*)   A((size_t)TT*HH*4);
  float*    xg     = (float*)   A((size_t)N1DN*HH*4);
  float*    x2     = (float*)   A((size_t)TT*HH*4);
  float*    h2f    = (float*)   A((size_t)TT*HH*4);
  float*    hist2  = (float*)   A((size_t)CHILDN*HH*4);
  float*    cnt    = (float*)   A((size_t)CHILDN*4);
  float*    abuf   = (float*)   A((size_t)TT*4);
  unsigned* amax   = (unsigned*)A((size_t)CHILDN*4);
  float*    aden   = (float*)   A((size_t)CHILDN*4);
  float*    x3     = (float*)   A((size_t)N1DN*HH*4);
  float*    cef    = (float*)   A((size_t)N4DN*HH*4);
  float*    psum   = (float*)   A((size_t)PARENTN*HH*4);
  float*    pcnt   = (float*)   A((size_t)PARENTN*4);
  int*      tokid  = (int*)     A((size_t)TT*4);
  int*      toknt  = (int*)     A((size_t)TT*4);
  int*      gnid2  = (int*)     A((size_t)N2N*4);
  int*      tsrc2  = (int*)     A((size_t)N2N*4);
  if(off > ws_size) return;  // insufficient scratch: out stays zero (finite absmax => diagnose as ws shortage)

  auto run_conv = [&](const float* src_h, const int* src_nid, const int* src_t, int nsrc,
                      const float* dst_h, const int* dst_t, int ndst,
                      const int* esrc, const int* edst, const int* ety, const int* ew, int E,
                      int layer, float* outbuf, float* out2, int relu){
    const float* KW  = convK  + (size_t)layer*NTY*HH*HH;
    const float* QW  = convQ  + (size_t)layer*NTY*HH*HH;
    const float* VW  = convV  + (size_t)layer*NTY*HH*HH;
    const float* OW  = convO  + (size_t)layer*NTY*HH*HH;
    const float* EWp = convE  + (size_t)layer*32*HH;
    const float* MU  = convMu + (size_t)layer*NRL*NH;
    k_conv_kv<<<nsrc, HH, 0, stream>>>(src_h, src_nid, src_t, dia_w, dia_b, KW, VW, Kbuf, Vbuf);
    k_conv_q<<<ndst, HH, 0, stream>>>(dst_h, dst_t, QW, Qbuf);
    k_conv_init<<<(ndst*HH+255)/256, 256, 0, stream>>>(Abuf, Dbuf, Mbuf, ndst);
    k_conv_score<<<(E+3)/4, 256, 0, stream>>>(esrc, edst, ety, ew, edge_emb, EWp, MU, Kbuf, Qbuf, Sbuf, Mbuf, E);
    k_conv_expsum<<<(E*8+255)/256, 256, 0, stream>>>(edst, Sbuf, Mbuf, Dbuf, E);
    k_conv_agg<<<(E+3)/4, 256, 0, stream>>>(esrc, edst, Sbuf, Dbuf, Vbuf, Abuf, E);
    k_conv_out<<<ndst, HH, 0, stream>>>(Abuf, dst_t, OW, dst_h, outbuf, out2, relu);
  };

  // ---- stage A: features + LSTM1 ----
  k_featx<<<TT, HH, 0, stream>>>(seq, dur, stime, etime, emb, dia_w, dia_b, t2v_w, t2v_b, exp_W, exp_b, xbuf);
  k_xwi<<<TT, 512, 0, stream>>>(xbuf, l1Wi, l1b, gpre);
  k_lstm<<<BB, 512, 0, stream>>>(gpre, l1Wh, h1, (float*)nullptr);
  k_tok<<<(TT+255)/256, 256, 0, stream>>>(seq, seq_nt, tokid, toknt);

  // ---- conv1 on g1 ----
  k_gather_emb<<<N1SN, HH, 0, stream>>>(g1_nid, emb, srcbuf);
  run_conv(srcbuf, g1_nid, g1_nt, N1SN, srcbuf, g1_nt, N1DN,
           g1_esrc, g1_edst, g1_ety, g1_ew, E1N, 0, xg, (float*)nullptr, 1);

  // ---- conv2 on g2 ----
  k_prep2<<<N2N, HH, 0, stream>>>(g2_sel, xg, g1_nid, g1_nt, srcbuf, gnid2, tsrc2);
  k_dst2<<<TT, HH, 0, stream>>>(tok_sel, xg, h1, dst2);
  run_conv(srcbuf, gnid2, tsrc2, N2N, dst2, toknt, TT,
           g2_esrc, g2_edst, g2_ety, g2_ew, E2N, 1, x2, (float*)nullptr, 1);

  // ---- LSTM2 (h2 is output 0) ----
  k_seq2<<<TT, HH, 0, stream>>>(x2, xbuf);
  k_xwi<<<TT, 512, 0, stream>>>(xbuf, l2Wi, l2b, gpre);
  k_lstm<<<BB, 512, 0, stream>>>(gpre, l2Wh, h2f, outp);

  // ---- stage D: token attention pooling -> hist2 ----
  k_zero_hist<<<(CHILDN*HH+255)/256, 256, 0, stream>>>(hist2, cnt, amax, aden);
  k_tokatt<<<TT, HH, 0, stream>>>(h2f, toknt, ipW, iaW, abuf, amax, tokid);
  k_tokexp<<<(TT+255)/256, 256, 0, stream>>>(tokid, abuf, amax, aden, cnt);
  k_tokagg<<<TT, HH, 0, stream>>>(tokid, abuf, aden, h2f, hist2);
  k_histfix<<<CHILDN, HH, 0, stream>>>(cnt, hist_emb, hist2);

  // ---- conv3 on g1 with skip-mixed input ----
  k_x0<<<N1SN, HH, 0, stream>>>(g1_nid, g1_nt, emb, hist2, skip, srcbuf);
  run_conv(srcbuf, g1_nid, g1_nt, N1SN, srcbuf, g1_nt, N1DN,
           g1_esrc, g1_edst, g1_ety, g1_ew, E1N, 2, x3, (float*)nullptr, 1);

  // ---- conv4 on g4 (child_embed = output 1, no relu) ----
  run_conv(x3, g1_nid, g1_nt, N1DN, x3, g1_nt, N4DN,
           g4_esrc, g4_edst, g4_ety, g4_ew, E4N, 3, cef, outp + (size_t)TT*HH, 0);

  // ---- parent pooling (output 2) ----
  k_zero_parent<<<(PARENTN*HH+255)/256, 256, 0, stream>>>(psum, pcnt);
  k_peagg<<<EC2PN, HH, 0, stream>>>(pe_p, pe_c, cef, psum, pcnt);
  k_parent<<<PARENTN, HH, 0, stream>>>(psum, pcnt, outp + (size_t)TT*HH + (size_t)N4DN*HH);
}